// Round 8
// baseline (418.082 us; speedup 1.0000x reference)
//
#include <hip/hip_runtime.h>
#include <hip/hip_bf16.h>

#define NN 50000
#define NE 1000000
#define DIM 64
#define NG 256
#define NBUCK 196        // ceil(NN/256) buckets of 256 dst nodes
#define ROUND 4096       // edges per block in hist2d/permute
#define NBLK 245         // ceil(NE/ROUND)
#define TOT2D (NBUCK * NBLK)   // 48020
#define SCANB 47         // ceil(TOT2D/1024)

// ---- pass 1: per-block bucket histogram -> hist[b*NBLK + blk] ----
__global__ __launch_bounds__(512) void hist2d_kernel(const int* __restrict__ dst,
                                                     int* __restrict__ hist) {
    __shared__ int h[NBUCK];
    int t = threadIdx.x;
    if (t < NBUCK) h[t] = 0;
    __syncthreads();
    int base = blockIdx.x * ROUND;
#pragma unroll
    for (int it = 0; it < 8; ++it) {
        int e = base + it * 512 + t;
        if (e < NE) atomicAdd(&h[dst[e] >> 8], 1);
    }
    __syncthreads();
    if (t < NBUCK) hist[t * NBLK + blockIdx.x] = h[t];
}

// ---- pass 2: flat exclusive scan of hist[TOT2D] ----
__global__ __launch_bounds__(1024) void scanA_kernel(const int* __restrict__ hist,
                                                     int* __restrict__ blocksum) {
    __shared__ int tmp[1024];
    int t = threadIdx.x;
    int i = blockIdx.x * 1024 + t;
    tmp[t] = (i < TOT2D) ? hist[i] : 0;
    __syncthreads();
    for (int s = 512; s > 0; s >>= 1) {
        if (t < s) tmp[t] += tmp[t + s];
        __syncthreads();
    }
    if (t == 0) blocksum[blockIdx.x] = tmp[0];
}

__global__ __launch_bounds__(64) void scanB_kernel(int* __restrict__ blocksum) {
    __shared__ int tmp[64];
    int t = threadIdx.x;
    int v = (t < SCANB) ? blocksum[t] : 0;
    tmp[t] = v;
    __syncthreads();
    for (int off = 1; off < 64; off <<= 1) {
        int a = (t >= off) ? tmp[t - off] : 0;
        __syncthreads();
        tmp[t] += a;
        __syncthreads();
    }
    if (t < SCANB) blocksum[t] = tmp[t] - v;   // exclusive
}

__global__ __launch_bounds__(1024) void scanC_kernel(const int* __restrict__ hist,
                                                     const int* __restrict__ blocksum,
                                                     int* __restrict__ scanned) {
    __shared__ int tmp[1024];
    int t = threadIdx.x;
    int i = blockIdx.x * 1024 + t;
    int v = (i < TOT2D) ? hist[i] : 0;
    tmp[t] = v;
    __syncthreads();
    for (int off = 1; off < 1024; off <<= 1) {
        int a = (t >= off) ? tmp[t - off] : 0;
        __syncthreads();
        tmp[t] += a;
        __syncthreads();
    }
    if (i < TOT2D) scanned[i] = tmp[t] - v + blocksum[blockIdx.x];
}

// ---- pass 3: permute edges into bucket-major order (no global atomics) ----
__global__ __launch_bounds__(512) void permute_kernel(
    const int* __restrict__ src, const int* __restrict__ dst,
    const int* __restrict__ scanned, unsigned int* __restrict__ bucketed) {
    __shared__ int cur[NBUCK];
    int t = threadIdx.x;
    int blk = blockIdx.x;
    if (t < NBUCK) cur[t] = scanned[t * NBLK + blk];
    __syncthreads();
    int base = blk * ROUND;
#pragma unroll
    for (int it = 0; it < 8; ++it) {
        int e = base + it * 512 + t;
        if (e < NE) {
            int d = dst[e];
            int s = src[e];
            int b = d >> 8;
            int pos = atomicAdd(&cur[b], 1);
            bucketed[pos] = ((unsigned int)(d & 255) << 16) | (unsigned int)s;
        }
    }
}

// ---- pass 4: per-bucket counting sort -> exact CSR ----
__global__ __launch_bounds__(512) void bucket_sort_kernel(
    const unsigned int* __restrict__ bucketed, const int* __restrict__ scanned,
    int* __restrict__ offsets, int* __restrict__ csr) {
    __shared__ int hist[256];
    __shared__ int sc[256];
    __shared__ int cur[256];
    int b = blockIdx.x;
    int t = threadIdx.x;
    if (t < 256) hist[t] = 0;
    __syncthreads();
    int gbase = scanned[b * NBLK];
    int gend  = (b < NBUCK - 1) ? scanned[(b + 1) * NBLK] : NE;
    int count = gend - gbase;
    const unsigned int* bd = bucketed + gbase;
    for (int e = t; e < count; e += 512) atomicAdd(&hist[bd[e] >> 16], 1);
    __syncthreads();
    if (t < 256) sc[t] = hist[t];
    __syncthreads();
    for (int off = 1; off < 256; off <<= 1) {
        int a = 0;
        if (t < 256 && t >= off) a = sc[t - off];
        __syncthreads();
        if (t < 256) sc[t] += a;
        __syncthreads();
    }
    if (t < 256) {
        int excl = sc[t] - hist[t];
        cur[t] = excl;
        int node = b * 256 + t;
        if (node < NN) offsets[node] = gbase + excl;
    }
    if (b == NBUCK - 1 && t == 0) offsets[NN] = NE;
    __syncthreads();
    for (int e = t; e < count; e += 512) {
        unsigned int v = bd[e];
        int p = atomicAdd(&cur[v >> 16], 1);
        csr[gbase + p] = (int)(v & 0xFFFFu);
    }
}

// ---------- H = X @ W -> bf16 : 256 thr, 128 rows/block, 32 cols/thread ----------
__global__ __launch_bounds__(256) void gemm64_kernel(const float* __restrict__ X,
                                                     const float* __restrict__ W,
                                                     __hip_bfloat16* __restrict__ H,
                                                     int nrows) {
    __shared__ float Xl[128 * 65];
    int t = threadIdx.x;
    int base = blockIdx.x * 128;
    for (int idx = t; idx < 128 * 16; idx += 256) {
        int row = idx >> 4;
        int c4  = idx & 15;
        float4 v = make_float4(0.f, 0.f, 0.f, 0.f);
        if (base + row < nrows)
            v = *reinterpret_cast<const float4*>(&X[(size_t)(base + row) * 64 + c4 * 4]);
        float* p = &Xl[row * 65 + c4 * 4];
        p[0] = v.x; p[1] = v.y; p[2] = v.z; p[3] = v.w;
    }
    __syncthreads();
    int r    = t >> 1;          // local row
    int half = t & 1;           // column half: [half*32, half*32+32)
    float acc[32];
#pragma unroll
    for (int c = 0; c < 32; ++c) acc[c] = 0.f;
#pragma unroll 4
    for (int k = 0; k < 64; ++k) {
        float xv = Xl[r * 65 + k];
#pragma unroll
        for (int c4 = 0; c4 < 8; ++c4) {
            float4 w = *reinterpret_cast<const float4*>(&W[k * 64 + half * 32 + c4 * 4]);
            acc[c4 * 4 + 0] = fmaf(xv, w.x, acc[c4 * 4 + 0]);
            acc[c4 * 4 + 1] = fmaf(xv, w.y, acc[c4 * 4 + 1]);
            acc[c4 * 4 + 2] = fmaf(xv, w.z, acc[c4 * 4 + 2]);
            acc[c4 * 4 + 3] = fmaf(xv, w.w, acc[c4 * 4 + 3]);
        }
    }
    int row = base + r;
    if (row < nrows) {
        alignas(16) __hip_bfloat16 hb[32];
#pragma unroll
        for (int c = 0; c < 32; ++c) hb[c] = __float2bfloat16(acc[c]);
        uint4* dst4 = reinterpret_cast<uint4*>(&H[(size_t)row * 64 + half * 32]);
        const uint4* src4 = reinterpret_cast<const uint4*>(hb);
#pragma unroll
        for (int q = 0; q < 4; ++q) dst4[q] = src4[q];
    }
}

// ---------- per-node CSR gather (bf16 H) + ReLU + batched add-pool ----------
template <bool WRITE_X>
__global__ void gather_kernel(const __hip_bfloat16* __restrict__ H,
                              const int* __restrict__ offsets,
                              const int* __restrict__ csr, const int* __restrict__ batch,
                              float* __restrict__ Xout, float* __restrict__ pool) {
    int tid = blockIdx.x * blockDim.x + threadIdx.x;
    int lane = tid & 63;
    int gw = tid >> 6;
    int nw = (gridDim.x * blockDim.x) >> 6;
    int chunk = (NN + nw - 1) / nw;           // contiguous nodes per wave
    int start = gw * chunk;
    if (start >= NN) return;
    int stop = min(start + chunk, NN);
    float pacc = 0.f;
    int curg = batch[start];
    for (int n = start; n < stop; ++n) {
        int beg = offsets[n], end = offsets[n + 1];
        float a0 = 0.f, a1 = 0.f, a2 = 0.f, a3 = 0.f;
        int i = beg;
        for (; i + 4 <= end; i += 4) {
            int s0 = csr[i], s1 = csr[i + 1], s2 = csr[i + 2], s3 = csr[i + 3];
            a0 += __bfloat162float(H[(size_t)s0 * 64 + lane]);
            a1 += __bfloat162float(H[(size_t)s1 * 64 + lane]);
            a2 += __bfloat162float(H[(size_t)s2 * 64 + lane]);
            a3 += __bfloat162float(H[(size_t)s3 * 64 + lane]);
        }
        for (; i < end; ++i) a0 += __bfloat162float(H[(size_t)csr[i] * 64 + lane]);
        float v = fmaxf((a0 + a1) + (a2 + a3), 0.f);
        if (WRITE_X) Xout[(size_t)n * 64 + lane] = v;
        int g = batch[n];
        if (g != curg) {                       // wave-uniform (batch sorted)
            unsafeAtomicAdd(&pool[(size_t)curg * 64 + lane], pacc);
            pacc = 0.f; curg = g;
        }
        pacc += v;
    }
    unsafeAtomicAdd(&pool[(size_t)curg * 64 + lane], pacc);
}

// ---------- out[g] = relu(sum_l pool_l[g] @ Wp_l) ----------
__global__ void final_kernel(const float* __restrict__ P1, const float* __restrict__ P2,
                             const float* __restrict__ P3,
                             const float* __restrict__ Wp1, const float* __restrict__ Wp2,
                             const float* __restrict__ Wp3, float* __restrict__ out) {
    int g = blockIdx.x;
    int c = threadIdx.x;  // 64
    float acc = 0.f;
#pragma unroll
    for (int k = 0; k < 64; ++k) {
        acc = fmaf(P1[g * 64 + k], Wp1[k * 64 + c], acc);
        acc = fmaf(P2[g * 64 + k], Wp2[k * 64 + c], acc);
        acc = fmaf(P3[g * 64 + k], Wp3[k * 64 + c], acc);
    }
    out[g * 64 + c] = fmaxf(acc, 0.f);
}

extern "C" void kernel_launch(void* const* d_in, const int* in_sizes, int n_in,
                              void* d_out, int out_size, void* d_ws, size_t ws_size,
                              hipStream_t stream) {
    const float* x     = (const float*)d_in[0];
    const int*   eidx  = (const int*)d_in[1];   // [2, NE]
    const int*   batch = (const int*)d_in[2];   // [NN], sorted
    const float* W1  = (const float*)d_in[3];
    const float* W2  = (const float*)d_in[4];
    const float* W3  = (const float*)d_in[5];
    const float* Wp1 = (const float*)d_in[6];
    const float* Wp2 = (const float*)d_in[7];
    const float* Wp3 = (const float*)d_in[8];
    float* out = (float*)d_out;

    const int* src = eidx;
    const int* dst = eidx + NE;

    // ---- workspace layout (~28 MB) ----
    __hip_bfloat16* bufH = (__hip_bfloat16*)d_ws;        // H bf16 (6.4 MB)
    float* bufX  = (float*)(bufH + (size_t)NN * DIM);    // x_l fp32 (12.8 MB)
    float* pool1 = bufX + (size_t)NN * DIM;              // 3 x 64 KB
    float* pool2 = pool1 + (size_t)NG * DIM;
    float* pool3 = pool2 + (size_t)NG * DIM;
    int* hist     = (int*)(pool3 + (size_t)NG * DIM);    // TOT2D
    int* scanned  = hist + TOT2D;                        // TOT2D
    int* blocksum = scanned + TOT2D;                     // 64
    int* offsets  = blocksum + 64;                       // NN+1
    unsigned int* bucketed = (unsigned int*)(offsets + NN + 1);  // NE (4 MB)
    int* csr      = (int*)(bucketed + NE);               // NE (4 MB)

    hipMemsetAsync(pool1, 0, (size_t)3 * NG * DIM * sizeof(float), stream);

    // ---- build exact CSR: hist -> scan -> permute -> bucket sort ----
    hist2d_kernel<<<NBLK, 512, 0, stream>>>(dst, hist);
    scanA_kernel<<<SCANB, 1024, 0, stream>>>(hist, blocksum);
    scanB_kernel<<<1, 64, 0, stream>>>(blocksum);
    scanC_kernel<<<SCANB, 1024, 0, stream>>>(hist, blocksum, scanned);
    permute_kernel<<<NBLK, 512, 0, stream>>>(src, dst, scanned, bucketed);
    bucket_sort_kernel<<<NBUCK, 512, 0, stream>>>(bucketed, scanned, offsets, csr);

    const int gemm_blocks = (NN + 127) / 128;           // 391
    const int gath_blocks = 2048;                        // 8192 waves, 7 nodes each

    // layer 1
    gemm64_kernel<<<gemm_blocks, 256, 0, stream>>>(x, W1, bufH, NN);
    gather_kernel<true><<<gath_blocks, 256, 0, stream>>>(bufH, offsets, csr, batch, bufX, pool1);
    // layer 2
    gemm64_kernel<<<gemm_blocks, 256, 0, stream>>>(bufX, W2, bufH, NN);
    gather_kernel<true><<<gath_blocks, 256, 0, stream>>>(bufH, offsets, csr, batch, bufX, pool2);
    // layer 3 (x3 only feeds the pool -> skip Xout write)
    gemm64_kernel<<<gemm_blocks, 256, 0, stream>>>(bufX, W3, bufH, NN);
    gather_kernel<false><<<gath_blocks, 256, 0, stream>>>(bufH, offsets, csr, batch, nullptr, pool3);

    final_kernel<<<NG, 64, 0, stream>>>(pool1, pool2, pool3, Wp1, Wp2, Wp3, out);
}

// Round 9
// 320.663 us; speedup vs baseline: 1.3038x; 1.3038x over previous
//
#include <hip/hip_runtime.h>
#include <hip/hip_bf16.h>

#define NN 50000
#define NE 1000000
#define DIM 64
#define NG 256
#define NBUCK 196        // ceil(NN/256) buckets of 256 dst nodes
#define ROUND 4096       // edges per block in hist2d/permute
#define NBLK 245         // ceil(NE/ROUND)
#define TOT2D (NBUCK * NBLK)   // 48020
#define SCANB 47         // ceil(TOT2D/1024)

// ---- pass 1: per-block bucket histogram -> hist[b*NBLK + blk] ----
__global__ __launch_bounds__(512) void hist2d_kernel(const int* __restrict__ dst,
                                                     int* __restrict__ hist) {
    __shared__ int h[NBUCK];
    int t = threadIdx.x;
    if (t < NBUCK) h[t] = 0;
    __syncthreads();
    int base = blockIdx.x * ROUND;
#pragma unroll
    for (int it = 0; it < 8; ++it) {
        int e = base + it * 512 + t;
        if (e < NE) atomicAdd(&h[dst[e] >> 8], 1);
    }
    __syncthreads();
    if (t < NBUCK) hist[t * NBLK + blockIdx.x] = h[t];
}

// ---- pass 2: flat exclusive scan of hist[TOT2D] ----
__global__ __launch_bounds__(1024) void scanA_kernel(const int* __restrict__ hist,
                                                     int* __restrict__ blocksum) {
    __shared__ int tmp[1024];
    int t = threadIdx.x;
    int i = blockIdx.x * 1024 + t;
    tmp[t] = (i < TOT2D) ? hist[i] : 0;
    __syncthreads();
    for (int s = 512; s > 0; s >>= 1) {
        if (t < s) tmp[t] += tmp[t + s];
        __syncthreads();
    }
    if (t == 0) blocksum[blockIdx.x] = tmp[0];
}

__global__ __launch_bounds__(64) void scanB_kernel(int* __restrict__ blocksum) {
    __shared__ int tmp[64];
    int t = threadIdx.x;
    int v = (t < SCANB) ? blocksum[t] : 0;
    tmp[t] = v;
    __syncthreads();
    for (int off = 1; off < 64; off <<= 1) {
        int a = (t >= off) ? tmp[t - off] : 0;
        __syncthreads();
        tmp[t] += a;
        __syncthreads();
    }
    if (t < SCANB) blocksum[t] = tmp[t] - v;   // exclusive
}

__global__ __launch_bounds__(1024) void scanC_kernel(const int* __restrict__ hist,
                                                     const int* __restrict__ blocksum,
                                                     int* __restrict__ scanned) {
    __shared__ int tmp[1024];
    int t = threadIdx.x;
    int i = blockIdx.x * 1024 + t;
    int v = (i < TOT2D) ? hist[i] : 0;
    tmp[t] = v;
    __syncthreads();
    for (int off = 1; off < 1024; off <<= 1) {
        int a = (t >= off) ? tmp[t - off] : 0;
        __syncthreads();
        tmp[t] += a;
        __syncthreads();
    }
    if (i < TOT2D) scanned[i] = tmp[t] - v + blocksum[blockIdx.x];
}

// ---- pass 3: permute edges into bucket-major order (no global atomics) ----
__global__ __launch_bounds__(512) void permute_kernel(
    const int* __restrict__ src, const int* __restrict__ dst,
    const int* __restrict__ scanned, unsigned int* __restrict__ bucketed) {
    __shared__ int cur[NBUCK];
    int t = threadIdx.x;
    int blk = blockIdx.x;
    if (t < NBUCK) cur[t] = scanned[t * NBLK + blk];
    __syncthreads();
    int base = blk * ROUND;
#pragma unroll
    for (int it = 0; it < 8; ++it) {
        int e = base + it * 512 + t;
        if (e < NE) {
            int d = dst[e];
            int s = src[e];
            int b = d >> 8;
            int pos = atomicAdd(&cur[b], 1);
            bucketed[pos] = ((unsigned int)(d & 255) << 16) | (unsigned int)s;
        }
    }
}

// ---- pass 4: per-bucket counting sort -> exact CSR ----
__global__ __launch_bounds__(512) void bucket_sort_kernel(
    const unsigned int* __restrict__ bucketed, const int* __restrict__ scanned,
    int* __restrict__ offsets, int* __restrict__ csr) {
    __shared__ int hist[256];
    __shared__ int sc[256];
    __shared__ int cur[256];
    int b = blockIdx.x;
    int t = threadIdx.x;
    if (t < 256) hist[t] = 0;
    __syncthreads();
    int gbase = scanned[b * NBLK];
    int gend  = (b < NBUCK - 1) ? scanned[(b + 1) * NBLK] : NE;
    int count = gend - gbase;
    const unsigned int* bd = bucketed + gbase;
    for (int e = t; e < count; e += 512) atomicAdd(&hist[bd[e] >> 16], 1);
    __syncthreads();
    if (t < 256) sc[t] = hist[t];
    __syncthreads();
    for (int off = 1; off < 256; off <<= 1) {
        int a = 0;
        if (t < 256 && t >= off) a = sc[t - off];
        __syncthreads();
        if (t < 256) sc[t] += a;
        __syncthreads();
    }
    if (t < 256) {
        int excl = sc[t] - hist[t];
        cur[t] = excl;
        int node = b * 256 + t;
        if (node < NN) offsets[node] = gbase + excl;
    }
    if (b == NBUCK - 1 && t == 0) offsets[NN] = NE;
    __syncthreads();
    for (int e = t; e < count; e += 512) {
        unsigned int v = bd[e];
        int p = atomicAdd(&cur[v >> 16], 1);
        csr[gbase + p] = (int)(v & 0xFFFFu);
    }
}

// ---------- H = X @ W -> bf16 : thread-per-row, W wave-uniform (s_load) ----------
__global__ __launch_bounds__(128) void gemm64_kernel(const float* __restrict__ X,
                                                     const float* __restrict__ W,
                                                     __hip_bfloat16* __restrict__ H,
                                                     int nrows) {
    __shared__ float Xl[128 * 65];   // +1 pad
    int t = threadIdx.x;
    int base = blockIdx.x * 128;
    for (int idx = t; idx < 128 * 16; idx += 128) {
        int row = idx >> 4;
        int c4  = idx & 15;
        float4 v = make_float4(0.f, 0.f, 0.f, 0.f);
        if (base + row < nrows)
            v = *reinterpret_cast<const float4*>(&X[(size_t)(base + row) * 64 + c4 * 4]);
        float* p = &Xl[row * 65 + c4 * 4];
        p[0] = v.x; p[1] = v.y; p[2] = v.z; p[3] = v.w;
    }
    __syncthreads();
    float acc[64];
#pragma unroll
    for (int c = 0; c < 64; ++c) acc[c] = 0.f;
#pragma unroll 4
    for (int k = 0; k < 64; ++k) {
        float xv = Xl[t * 65 + k];
#pragma unroll
        for (int c4 = 0; c4 < 16; ++c4) {
            float4 w = *reinterpret_cast<const float4*>(&W[k * 64 + c4 * 4]); // uniform -> s_load
            acc[c4 * 4 + 0] = fmaf(xv, w.x, acc[c4 * 4 + 0]);
            acc[c4 * 4 + 1] = fmaf(xv, w.y, acc[c4 * 4 + 1]);
            acc[c4 * 4 + 2] = fmaf(xv, w.z, acc[c4 * 4 + 2]);
            acc[c4 * 4 + 3] = fmaf(xv, w.w, acc[c4 * 4 + 3]);
        }
    }
    int row = base + t;
    if (row < nrows) {
        alignas(16) __hip_bfloat16 hb[64];
#pragma unroll
        for (int c = 0; c < 64; ++c) hb[c] = __float2bfloat16(acc[c]);
        uint4* dst4 = reinterpret_cast<uint4*>(&H[(size_t)row * 64]);
        const uint4* src4 = reinterpret_cast<const uint4*>(hb);
#pragma unroll
        for (int q = 0; q < 8; ++q) dst4[q] = src4[q];
    }
}

// ---------- per-node CSR gather (bf16 H) + ReLU + batched add-pool ----------
template <bool WRITE_X>
__global__ void gather_kernel(const __hip_bfloat16* __restrict__ H,
                              const int* __restrict__ offsets,
                              const int* __restrict__ csr, const int* __restrict__ batch,
                              float* __restrict__ Xout, float* __restrict__ pool) {
    int tid = blockIdx.x * blockDim.x + threadIdx.x;
    int lane = tid & 63;
    int gw = tid >> 6;
    int nw = (gridDim.x * blockDim.x) >> 6;
    int chunk = (NN + nw - 1) / nw;           // contiguous nodes per wave
    int start = gw * chunk;
    if (start >= NN) return;
    int stop = min(start + chunk, NN);
    float pacc = 0.f;
    int curg = batch[start];
    for (int n = start; n < stop; ++n) {
        int beg = offsets[n], end = offsets[n + 1];
        float a0 = 0.f, a1 = 0.f, a2 = 0.f, a3 = 0.f;
        int i = beg;
        for (; i + 4 <= end; i += 4) {
            int s0 = csr[i], s1 = csr[i + 1], s2 = csr[i + 2], s3 = csr[i + 3];
            a0 += __bfloat162float(H[(size_t)s0 * 64 + lane]);
            a1 += __bfloat162float(H[(size_t)s1 * 64 + lane]);
            a2 += __bfloat162float(H[(size_t)s2 * 64 + lane]);
            a3 += __bfloat162float(H[(size_t)s3 * 64 + lane]);
        }
        for (; i < end; ++i) a0 += __bfloat162float(H[(size_t)csr[i] * 64 + lane]);
        float v = fmaxf((a0 + a1) + (a2 + a3), 0.f);
        if (WRITE_X) Xout[(size_t)n * 64 + lane] = v;
        int g = batch[n];
        if (g != curg) {                       // wave-uniform (batch sorted)
            unsafeAtomicAdd(&pool[(size_t)curg * 64 + lane], pacc);
            pacc = 0.f; curg = g;
        }
        pacc += v;
    }
    unsafeAtomicAdd(&pool[(size_t)curg * 64 + lane], pacc);
}

// ---------- out[g] = relu(sum_l pool_l[g] @ Wp_l) ----------
__global__ void final_kernel(const float* __restrict__ P1, const float* __restrict__ P2,
                             const float* __restrict__ P3,
                             const float* __restrict__ Wp1, const float* __restrict__ Wp2,
                             const float* __restrict__ Wp3, float* __restrict__ out) {
    int g = blockIdx.x;
    int c = threadIdx.x;  // 64
    float acc = 0.f;
#pragma unroll
    for (int k = 0; k < 64; ++k) {
        acc = fmaf(P1[g * 64 + k], Wp1[k * 64 + c], acc);
        acc = fmaf(P2[g * 64 + k], Wp2[k * 64 + c], acc);
        acc = fmaf(P3[g * 64 + k], Wp3[k * 64 + c], acc);
    }
    out[g * 64 + c] = fmaxf(acc, 0.f);
}

extern "C" void kernel_launch(void* const* d_in, const int* in_sizes, int n_in,
                              void* d_out, int out_size, void* d_ws, size_t ws_size,
                              hipStream_t stream) {
    const float* x     = (const float*)d_in[0];
    const int*   eidx  = (const int*)d_in[1];   // [2, NE]
    const int*   batch = (const int*)d_in[2];   // [NN], sorted
    const float* W1  = (const float*)d_in[3];
    const float* W2  = (const float*)d_in[4];
    const float* W3  = (const float*)d_in[5];
    const float* Wp1 = (const float*)d_in[6];
    const float* Wp2 = (const float*)d_in[7];
    const float* Wp3 = (const float*)d_in[8];
    float* out = (float*)d_out;

    const int* src = eidx;
    const int* dst = eidx + NE;

    // ---- workspace layout (~28 MB) ----
    __hip_bfloat16* bufH = (__hip_bfloat16*)d_ws;        // H bf16 (6.4 MB)
    float* bufX  = (float*)(bufH + (size_t)NN * DIM);    // x_l fp32 (12.8 MB)
    float* pool1 = bufX + (size_t)NN * DIM;              // 3 x 64 KB
    float* pool2 = pool1 + (size_t)NG * DIM;
    float* pool3 = pool2 + (size_t)NG * DIM;
    int* hist     = (int*)(pool3 + (size_t)NG * DIM);    // TOT2D
    int* scanned  = hist + TOT2D;                        // TOT2D
    int* blocksum = scanned + TOT2D;                     // 64
    int* offsets  = blocksum + 64;                       // NN+1
    unsigned int* bucketed = (unsigned int*)(offsets + NN + 1);  // NE (4 MB)
    int* csr      = (int*)(bucketed + NE);               // NE (4 MB)

    hipMemsetAsync(pool1, 0, (size_t)3 * NG * DIM * sizeof(float), stream);

    // ---- build exact CSR: hist -> scan -> permute -> bucket sort ----
    hist2d_kernel<<<NBLK, 512, 0, stream>>>(dst, hist);
    scanA_kernel<<<SCANB, 1024, 0, stream>>>(hist, blocksum);
    scanB_kernel<<<1, 64, 0, stream>>>(blocksum);
    scanC_kernel<<<SCANB, 1024, 0, stream>>>(hist, blocksum, scanned);
    permute_kernel<<<NBLK, 512, 0, stream>>>(src, dst, scanned, bucketed);
    bucket_sort_kernel<<<NBUCK, 512, 0, stream>>>(bucketed, scanned, offsets, csr);

    const int gemm_blocks = (NN + 127) / 128;           // 391
    const int gath_blocks = 2048;                        // 8192 waves, 7 nodes each

    // layer 1
    gemm64_kernel<<<gemm_blocks, 128, 0, stream>>>(x, W1, bufH, NN);
    gather_kernel<true><<<gath_blocks, 256, 0, stream>>>(bufH, offsets, csr, batch, bufX, pool1);
    // layer 2
    gemm64_kernel<<<gemm_blocks, 128, 0, stream>>>(bufX, W2, bufH, NN);
    gather_kernel<true><<<gath_blocks, 256, 0, stream>>>(bufH, offsets, csr, batch, bufX, pool2);
    // layer 3 (x3 only feeds the pool -> skip Xout write)
    gemm64_kernel<<<gemm_blocks, 128, 0, stream>>>(bufX, W3, bufH, NN);
    gather_kernel<false><<<gath_blocks, 256, 0, stream>>>(bufH, offsets, csr, batch, nullptr, pool3);

    final_kernel<<<NG, 64, 0, stream>>>(pool1, pool2, pool3, Wp1, Wp2, Wp3, out);
}

// Round 11
// 295.390 us; speedup vs baseline: 1.4154x; 1.0856x over previous
//
#include <hip/hip_runtime.h>
#include <hip/hip_bf16.h>

#define NN 50000
#define NE 1000000
#define DIM 64
#define NG 256
#define NBUCK 196        // ceil(NN/256) buckets of 256 dst nodes
#define ROUND 4096       // edges per block in hist2d/permute
#define NBLK 245         // ceil(NE/ROUND)
#define TOT2D (NBUCK * NBLK)   // 48020
#define SCANB 47         // ceil(TOT2D/1024)

// ---- pass 1: per-block bucket histogram -> hist[b*NBLK + blk]; also zeros pool ----
__global__ __launch_bounds__(512) void hist2d_kernel(const int* __restrict__ dst,
                                                     int* __restrict__ hist,
                                                     float* __restrict__ pool) {
    // fold pool-zeroing into this kernel (runs before any gather)
    int gtid = blockIdx.x * 512 + threadIdx.x;
    for (int i = gtid; i < 3 * NG * DIM; i += NBLK * 512) pool[i] = 0.f;

    __shared__ int h[NBUCK];
    int t = threadIdx.x;
    if (t < NBUCK) h[t] = 0;
    __syncthreads();
    int base = blockIdx.x * ROUND;
#pragma unroll
    for (int it = 0; it < 8; ++it) {
        int e = base + it * 512 + t;
        if (e < NE) atomicAdd(&h[dst[e] >> 8], 1);
    }
    __syncthreads();
    if (t < NBUCK) hist[t * NBLK + blockIdx.x] = h[t];
}

// ---- pass 2: flat exclusive scan of hist[TOT2D] ----
__global__ __launch_bounds__(1024) void scanA_kernel(const int* __restrict__ hist,
                                                     int* __restrict__ blocksum) {
    __shared__ int tmp[1024];
    int t = threadIdx.x;
    int i = blockIdx.x * 1024 + t;
    tmp[t] = (i < TOT2D) ? hist[i] : 0;
    __syncthreads();
    for (int s = 512; s > 0; s >>= 1) {
        if (t < s) tmp[t] += tmp[t + s];
        __syncthreads();
    }
    if (t == 0) blocksum[blockIdx.x] = tmp[0];
}

__global__ __launch_bounds__(64) void scanB_kernel(int* __restrict__ blocksum) {
    __shared__ int tmp[64];
    int t = threadIdx.x;
    int v = (t < SCANB) ? blocksum[t] : 0;
    tmp[t] = v;
    __syncthreads();
    for (int off = 1; off < 64; off <<= 1) {
        int a = (t >= off) ? tmp[t - off] : 0;
        __syncthreads();
        tmp[t] += a;
        __syncthreads();
    }
    if (t < SCANB) blocksum[t] = tmp[t] - v;   // exclusive
}

__global__ __launch_bounds__(1024) void scanC_kernel(const int* __restrict__ hist,
                                                     const int* __restrict__ blocksum,
                                                     int* __restrict__ scanned) {
    __shared__ int tmp[1024];
    int t = threadIdx.x;
    int i = blockIdx.x * 1024 + t;
    int v = (i < TOT2D) ? hist[i] : 0;
    tmp[t] = v;
    __syncthreads();
    for (int off = 1; off < 1024; off <<= 1) {
        int a = (t >= off) ? tmp[t - off] : 0;
        __syncthreads();
        tmp[t] += a;
        __syncthreads();
    }
    if (i < TOT2D) scanned[i] = tmp[t] - v + blocksum[blockIdx.x];
}

// ---- pass 3: permute edges into bucket-major order (no global atomics) ----
__global__ __launch_bounds__(512) void permute_kernel(
    const int* __restrict__ src, const int* __restrict__ dst,
    const int* __restrict__ scanned, unsigned int* __restrict__ bucketed) {
    __shared__ int cur[NBUCK];
    int t = threadIdx.x;
    int blk = blockIdx.x;
    if (t < NBUCK) cur[t] = scanned[t * NBLK + blk];
    __syncthreads();
    int base = blk * ROUND;
#pragma unroll
    for (int it = 0; it < 8; ++it) {
        int e = base + it * 512 + t;
        if (e < NE) {
            int d = dst[e];
            int s = src[e];
            int b = d >> 8;
            int pos = atomicAdd(&cur[b], 1);
            bucketed[pos] = ((unsigned int)(d & 255) << 16) | (unsigned int)s;
        }
    }
}

// ---- pass 4: per-bucket counting sort -> exact CSR ----
__global__ __launch_bounds__(512) void bucket_sort_kernel(
    const unsigned int* __restrict__ bucketed, const int* __restrict__ scanned,
    int* __restrict__ offsets, int* __restrict__ csr) {
    __shared__ int hist[256];
    __shared__ int sc[256];
    __shared__ int cur[256];
    int b = blockIdx.x;
    int t = threadIdx.x;
    if (t < 256) hist[t] = 0;
    __syncthreads();
    int gbase = scanned[b * NBLK];
    int gend  = (b < NBUCK - 1) ? scanned[(b + 1) * NBLK] : NE;
    int count = gend - gbase;
    const unsigned int* bd = bucketed + gbase;
    for (int e = t; e < count; e += 512) atomicAdd(&hist[bd[e] >> 16], 1);
    __syncthreads();
    if (t < 256) sc[t] = hist[t];
    __syncthreads();
    for (int off = 1; off < 256; off <<= 1) {
        int a = 0;
        if (t < 256 && t >= off) a = sc[t - off];
        __syncthreads();
        if (t < 256) sc[t] += a;
        __syncthreads();
    }
    if (t < 256) {
        int excl = sc[t] - hist[t];
        cur[t] = excl;
        int node = b * 256 + t;
        if (node < NN) offsets[node] = gbase + excl;
    }
    if (b == NBUCK - 1 && t == 0) offsets[NN] = NE;
    __syncthreads();
    for (int e = t; e < count; e += 512) {
        unsigned int v = bd[e];
        int p = atomicAdd(&cur[v >> 16], 1);
        csr[gbase + p] = (int)(v & 0xFFFFu);
    }
}

// ---------- H = X @ W -> bf16 : thread-per-row, W wave-uniform (s_load) ----------
__global__ __launch_bounds__(128) void gemm64_kernel(const float* __restrict__ X,
                                                     const float* __restrict__ W,
                                                     __hip_bfloat16* __restrict__ H,
                                                     int nrows) {
    __shared__ float Xl[128 * 65];   // +1 pad
    int t = threadIdx.x;
    int base = blockIdx.x * 128;
    for (int idx = t; idx < 128 * 16; idx += 128) {
        int row = idx >> 4;
        int c4  = idx & 15;
        float4 v = make_float4(0.f, 0.f, 0.f, 0.f);
        if (base + row < nrows)
            v = *reinterpret_cast<const float4*>(&X[(size_t)(base + row) * 64 + c4 * 4]);
        float* p = &Xl[row * 65 + c4 * 4];
        p[0] = v.x; p[1] = v.y; p[2] = v.z; p[3] = v.w;
    }
    __syncthreads();
    float acc[64];
#pragma unroll
    for (int c = 0; c < 64; ++c) acc[c] = 0.f;
#pragma unroll 4
    for (int k = 0; k < 64; ++k) {
        float xv = Xl[t * 65 + k];
#pragma unroll
        for (int c4 = 0; c4 < 16; ++c4) {
            float4 w = *reinterpret_cast<const float4*>(&W[k * 64 + c4 * 4]); // uniform -> s_load
            acc[c4 * 4 + 0] = fmaf(xv, w.x, acc[c4 * 4 + 0]);
            acc[c4 * 4 + 1] = fmaf(xv, w.y, acc[c4 * 4 + 1]);
            acc[c4 * 4 + 2] = fmaf(xv, w.z, acc[c4 * 4 + 2]);
            acc[c4 * 4 + 3] = fmaf(xv, w.w, acc[c4 * 4 + 3]);
        }
    }
    int row = base + t;
    if (row < nrows) {
        alignas(16) __hip_bfloat16 hb[64];
#pragma unroll
        for (int c = 0; c < 64; ++c) hb[c] = __float2bfloat16(acc[c]);
        uint4* dst4 = reinterpret_cast<uint4*>(&H[(size_t)row * 64]);
        const uint4* src4 = reinterpret_cast<const uint4*>(hb);
#pragma unroll
        for (int q = 0; q < 8; ++q) dst4[q] = src4[q];
    }
}

// ---------- per-node CSR gather (bf16 H, 8-deep MLP) + ReLU + batched add-pool ----------
template <bool WRITE_X>
__global__ void gather_kernel(const __hip_bfloat16* __restrict__ H,
                              const int* __restrict__ offsets,
                              const int* __restrict__ csr, const int* __restrict__ batch,
                              float* __restrict__ Xout, float* __restrict__ pool) {
    int tid = blockIdx.x * blockDim.x + threadIdx.x;
    int lane = tid & 63;
    int gw = tid >> 6;
    int nw = (gridDim.x * blockDim.x) >> 6;
    int chunk = (NN + nw - 1) / nw;           // contiguous nodes per wave
    int start = gw * chunk;
    if (start >= NN) return;
    int stop = min(start + chunk, NN);
    float pacc = 0.f;
    int curg = batch[start];
    for (int n = start; n < stop; ++n) {
        int beg = offsets[n], end = offsets[n + 1];
        float a0 = 0.f, a1 = 0.f, a2 = 0.f, a3 = 0.f;
        float a4 = 0.f, a5 = 0.f, a6 = 0.f, a7 = 0.f;
        int i = beg;
        for (; i + 8 <= end; i += 8) {        // 8 independent loads in flight
            int s0 = csr[i],     s1 = csr[i + 1], s2 = csr[i + 2], s3 = csr[i + 3];
            int s4 = csr[i + 4], s5 = csr[i + 5], s6 = csr[i + 6], s7 = csr[i + 7];
            a0 += __bfloat162float(H[(size_t)s0 * 64 + lane]);
            a1 += __bfloat162float(H[(size_t)s1 * 64 + lane]);
            a2 += __bfloat162float(H[(size_t)s2 * 64 + lane]);
            a3 += __bfloat162float(H[(size_t)s3 * 64 + lane]);
            a4 += __bfloat162float(H[(size_t)s4 * 64 + lane]);
            a5 += __bfloat162float(H[(size_t)s5 * 64 + lane]);
            a6 += __bfloat162float(H[(size_t)s6 * 64 + lane]);
            a7 += __bfloat162float(H[(size_t)s7 * 64 + lane]);
        }
        if (i + 4 <= end) {
            int s0 = csr[i], s1 = csr[i + 1], s2 = csr[i + 2], s3 = csr[i + 3];
            a0 += __bfloat162float(H[(size_t)s0 * 64 + lane]);
            a1 += __bfloat162float(H[(size_t)s1 * 64 + lane]);
            a2 += __bfloat162float(H[(size_t)s2 * 64 + lane]);
            a3 += __bfloat162float(H[(size_t)s3 * 64 + lane]);
            i += 4;
        }
        for (; i < end; ++i) a0 += __bfloat162float(H[(size_t)csr[i] * 64 + lane]);
        float v = fmaxf(((a0 + a1) + (a2 + a3)) + ((a4 + a5) + (a6 + a7)), 0.f);
        if (WRITE_X) Xout[(size_t)n * 64 + lane] = v;
        int g = batch[n];
        if (g != curg) {                       // wave-uniform (batch sorted)
            unsafeAtomicAdd(&pool[(size_t)curg * 64 + lane], pacc);
            pacc = 0.f; curg = g;
        }
        pacc += v;
    }
    unsafeAtomicAdd(&pool[(size_t)curg * 64 + lane], pacc);
}

// ---------- out[g] = relu(sum_l pool_l[g] @ Wp_l) ----------
__global__ void final_kernel(const float* __restrict__ P1, const float* __restrict__ P2,
                             const float* __restrict__ P3,
                             const float* __restrict__ Wp1, const float* __restrict__ Wp2,
                             const float* __restrict__ Wp3, float* __restrict__ out) {
    int g = blockIdx.x;
    int c = threadIdx.x;  // 64
    float acc = 0.f;
#pragma unroll
    for (int k = 0; k < 64; ++k) {
        acc = fmaf(P1[g * 64 + k], Wp1[k * 64 + c], acc);
        acc = fmaf(P2[g * 64 + k], Wp2[k * 64 + c], acc);
        acc = fmaf(P3[g * 64 + k], Wp3[k * 64 + c], acc);
    }
    out[g * 64 + c] = fmaxf(acc, 0.f);
}

extern "C" void kernel_launch(void* const* d_in, const int* in_sizes, int n_in,
                              void* d_out, int out_size, void* d_ws, size_t ws_size,
                              hipStream_t stream) {
    const float* x     = (const float*)d_in[0];
    const int*   eidx  = (const int*)d_in[1];   // [2, NE]
    const int*   batch = (const int*)d_in[2];   // [NN], sorted
    const float* W1  = (const float*)d_in[3];
    const float* W2  = (const float*)d_in[4];
    const float* W3  = (const float*)d_in[5];
    const float* Wp1 = (const float*)d_in[6];
    const float* Wp2 = (const float*)d_in[7];
    const float* Wp3 = (const float*)d_in[8];
    float* out = (float*)d_out;

    const int* src = eidx;
    const int* dst = eidx + NE;

    // ---- workspace layout (~28 MB) ----
    __hip_bfloat16* bufH = (__hip_bfloat16*)d_ws;        // H bf16 (6.4 MB)
    float* bufX  = (float*)(bufH + (size_t)NN * DIM);    // x_l fp32 (12.8 MB)
    float* pool1 = bufX + (size_t)NN * DIM;              // 3 x 64 KB
    float* pool2 = pool1 + (size_t)NG * DIM;
    float* pool3 = pool2 + (size_t)NG * DIM;
    int* hist     = (int*)(pool3 + (size_t)NG * DIM);    // TOT2D
    int* scanned  = hist + TOT2D;                        // TOT2D
    int* blocksum = scanned + TOT2D;                     // 64
    int* offsets  = blocksum + 64;                       // NN+1
    unsigned int* bucketed = (unsigned int*)(offsets + NN + 1);  // NE (4 MB)
    int* csr      = (int*)(bucketed + NE);               // NE (4 MB)

    // ---- build exact CSR: hist(+pool zero) -> scan -> permute -> bucket sort ----
    hist2d_kernel<<<NBLK, 512, 0, stream>>>(dst, hist, pool1);
    scanA_kernel<<<SCANB, 1024, 0, stream>>>(hist, blocksum);
    scanB_kernel<<<1, 64, 0, stream>>>(blocksum);
    scanC_kernel<<<SCANB, 1024, 0, stream>>>(hist, blocksum, scanned);
    permute_kernel<<<NBLK, 512, 0, stream>>>(src, dst, scanned, bucketed);
    bucket_sort_kernel<<<NBUCK, 512, 0, stream>>>(bucketed, scanned, offsets, csr);

    const int gemm_blocks = (NN + 127) / 128;           // 391
    const int gath_blocks = 1792;                        // 7168 waves, 7 nodes each

    // layer 1
    gemm64_kernel<<<gemm_blocks, 128, 0, stream>>>(x, W1, bufH, NN);
    gather_kernel<true><<<gath_blocks, 256, 0, stream>>>(bufH, offsets, csr, batch, bufX, pool1);
    // layer 2
    gemm64_kernel<<<gemm_blocks, 128, 0, stream>>>(bufX, W2, bufH, NN);
    gather_kernel<true><<<gath_blocks, 256, 0, stream>>>(bufH, offsets, csr, batch, bufX, pool2);
    // layer 3 (x3 only feeds the pool -> skip Xout write)
    gemm64_kernel<<<gemm_blocks, 128, 0, stream>>>(bufX, W3, bufH, NN);
    gather_kernel<false><<<gath_blocks, 256, 0, stream>>>(bufH, offsets, csr, batch, nullptr, pool3);

    final_kernel<<<NG, 64, 0, stream>>>(pool1, pool2, pool3, Wp1, Wp2, Wp3, out);
}